// Round 6
// baseline (414.799 us; speedup 1.0000x reference)
//
#include <hip/hip_runtime.h>
#include <hip/hip_bf16.h>

typedef __bf16 bf16_t;
typedef __bf16 bf16x8 __attribute__((ext_vector_type(8)));
typedef float floatx4 __attribute__((ext_vector_type(4)));

#define T_TOK 1024
#define DIM   1024
#define FF    512
#define NEXP  16

// ws layout
#define FLAG_OFF 0                 // int[6]
#define CNT_OFF  64                // int[16]
#define HOFF_OFF 192               // int[16] padded prefix of cnt
#define TOK_OFF  256               // int[16*1024], entry = token | (slot<<16)
#define H_OFF    65792             // bf16[3328][512] = 3,407,872 B
#define WS_NEED  (H_OFF + 3328*512*2)

__device__ inline float swiglu(float g, float u) {
    float a = fminf(fmaxf(-g, -60.f), 60.f);
    return g * u / (1.0f + __expf(a));
}

// ---------------- per-input dtype detect (verified r4) ----------------
__global__ __launch_bounds__(64) void detect_kernel(
    const void* p0, const void* p1, const void* p2,
    const void* p3, const void* p4, const void* p5,
    int* __restrict__ flags)
{
    const void* ps[6] = {p0, p1, p2, p3, p4, p5};
    int lane = threadIdx.x;
    for (int j = 0; j < 6; j++) {
        const unsigned short* h = (const unsigned short*)ps[j];
        unsigned int bad = 0;
        for (int i = lane; i < 4096; i += 64) {
            unsigned int e = ((unsigned int)h[i] >> 7) & 0xFFu;
            if (e >= 0x90u) bad = 1;
        }
        unsigned long long b = __ballot(bad);
        if (lane == 0) flags[j] = (b != 0ull) ? 1 : 0;
    }
}

// ---- runtime-typed loaders ----
__device__ inline void load16fr(const void* base, size_t off, float* o, bool f32) {
    if (f32) {
        const float4* p = (const float4*)((const float*)base + off);
        float4 v0 = p[0], v1 = p[1], v2 = p[2], v3 = p[3];
        o[0]=v0.x; o[1]=v0.y; o[2]=v0.z; o[3]=v0.w;
        o[4]=v1.x; o[5]=v1.y; o[6]=v1.z; o[7]=v1.w;
        o[8]=v2.x; o[9]=v2.y; o[10]=v2.z; o[11]=v2.w;
        o[12]=v3.x; o[13]=v3.y; o[14]=v3.z; o[15]=v3.w;
    } else {
        const bf16x8* p = (const bf16x8*)((const bf16_t*)base + off);
        bf16x8 a = p[0], b = p[1];
        #pragma unroll
        for (int i = 0; i < 8; i++) { o[i] = (float)a[i]; o[8+i] = (float)b[i]; }
    }
}

__device__ inline bf16x8 loadB8r(const void* base, size_t off, bool f32) {
    if (f32) {
        const float4* p = (const float4*)((const float*)base + off);
        float4 v0 = p[0], v1 = p[1];
        bf16x8 r;
        r[0]=(bf16_t)v0.x; r[1]=(bf16_t)v0.y; r[2]=(bf16_t)v0.z; r[3]=(bf16_t)v0.w;
        r[4]=(bf16_t)v1.x; r[5]=(bf16_t)v1.y; r[6]=(bf16_t)v1.z; r[7]=(bf16_t)v1.w;
        return r;
    } else {
        return *(const bf16x8*)((const bf16_t*)base + off);
    }
}

// ---------------- Router: 4 waves per token, 6 gates per wave ----------------
__global__ __launch_bounds__(256) void router_kernel(
    const void* __restrict__ x,
    const void* __restrict__ w_out,   // [8,1024]
    const void* __restrict__ w_in,    // [16,1024]
    float* __restrict__ selw_out,     // [T,3] fp32
    const int* __restrict__ flags,
    int* __restrict__ cnt, int* __restrict__ tok_enc)
{
    const bool xf  = flags[0] != 0;
    const bool gof = flags[1] != 0;
    const bool gif = flags[2] != 0;
    const int t = blockIdx.x;
    const int tid = threadIdx.x;
    const int wave = tid >> 6, lane = tid & 63;

    float xv[16];
    load16fr(x, (size_t)t * DIM + lane * 16, xv, xf);

    __shared__ float logits[24];
    for (int j = wave; j < 24; j += 4) {
        const void* grow = (j < 8) ? w_out : w_in;
        size_t roff = (j < 8) ? (size_t)j * DIM : (size_t)(j - 8) * DIM;
        float gv[16];
        load16fr(grow, roff + lane * 16, gv, (j < 8) ? gof : gif);
        float s = 0.f;
        #pragma unroll
        for (int i = 0; i < 16; i++) s += xv[i] * gv[i];
        #pragma unroll
        for (int m = 32; m >= 1; m >>= 1) s += __shfl_xor(s, m, 64);
        if (lane == 0) logits[j] = s;
    }
    __syncthreads();

    if (tid == 0) {
        float mx = logits[0];
        for (int o = 1; o < 8; o++) mx = fmaxf(mx, logits[o]);
        float p[8];
        for (int o = 0; o < 8; o++) p[o] = __expf(logits[o] - mx);
        int i0 = 0;
        for (int o = 1; o < 8; o++) if (logits[o] > logits[i0]) i0 = o;
        int i1 = (i0 == 0) ? 1 : 0;
        for (int o = 0; o < 8; o++) if (o != i0 && logits[o] > logits[i1]) i1 = o;
        float rsum = p[i0] + p[i1];
        float rw0 = p[i0] / rsum, rw1 = p[i1] / rsum;

        float a0 = logits[8 + i0 * 2], a1 = logits[8 + i0 * 2 + 1];
        int j00 = (a1 > a0) ? 1 : 0;
        float b0 = logits[8 + i1 * 2], b1 = logits[8 + i1 * 2 + 1];
        int j10 = (b1 > b0) ? 1 : 0;

        int   ids[3] = { i0 * 2 + j00, i0 * 2 + (1 - j00), i1 * 2 + j10 };
        float w[3]   = { rw0, rw0, rw1 };

        #pragma unroll
        for (int k = 0; k < 3; k++) {
            selw_out[t * 3 + k] = w[k];
            int e = ids[k];
            int pos = atomicAdd(&cnt[e], 1);
            if (pos >= 0 && pos < T_TOK)
                tok_enc[e * T_TOK + pos] = t | (k << 16);
        }
    }
}

// ---------------- tiny: padded prefix offsets ----------------
__global__ __launch_bounds__(64) void hoff_kernel(const int* __restrict__ cnt,
                                                  int* __restrict__ hoff) {
    if (threadIdx.x == 0) {
        int run = 0;
        for (int e = 0; e < NEXP; e++) {
            hoff[e] = run;
            int c = cnt[e]; if (c < 0) c = 0; if (c > T_TOK) c = T_TOK;
            run += (c + 15) & ~15;
        }
    }
}

// ---- gate+up+SwiGLU -> H : grid (e, mtile, ftile=8) ----
// Wave owns one 16-col f-tile of both gate and up. K chunked through LDS
// (4 x 256) to keep LDS at 8.4 KB; K split into 2 halves per chunk for
// 4 independent MFMA chains (ILP).
__global__ __launch_bounds__(256, 4) void gateup_kernel(
    const void* __restrict__ x,
    const void* __restrict__ wg, const void* __restrict__ wu,
    const int* __restrict__ flags, const int* __restrict__ cnt,
    const int* __restrict__ hoff, const int* __restrict__ tok_enc,
    bf16_t* __restrict__ H)
{
    const int e = blockIdx.x, mt = blockIdx.y, ft = blockIdx.z;
    int C = cnt[e]; if (C > T_TOK) C = T_TOK; if (C < 0) C = 0;
    if (mt * 16 >= C) return;
    const bool xf = flags[0] != 0, gf = flags[3] != 0, uf = flags[4] != 0;

    __shared__ __align__(16) bf16_t Xs[16][264];   // one 256-wide K chunk
    __shared__ int toks[16];
    const int tid = threadIdx.x;
    if (tid < 16) {
        int idx = mt * 16 + tid, t = -1;
        if (idx < C) { int enc = tok_enc[e * T_TOK + idx]; int tt = enc & 0xFFFF; if (tt < T_TOK) t = tt; }
        toks[tid] = t;
    }

    const int wave = tid >> 6, lane = tid & 63;
    const int rsel = lane & 15, kq = lane >> 4;
    const int srow = tid >> 4, sseg = tid & 15;     // staging row/segment
    const size_t eoffF = (size_t)e * FF * DIM;
    const int f0 = ft * 64 + wave * 16;
    const size_t boff = eoffF + (size_t)(f0 + rsel) * DIM + kq * 8;

    floatx4 accg0 = {0,0,0,0}, accg1 = {0,0,0,0};
    floatx4 accu0 = {0,0,0,0}, accu1 = {0,0,0,0};

    for (int kb = 0; kb < 4; kb++) {
        __syncthreads();
        // stage 16 x 256 chunk: each thread 16 elems
        {
            int t = toks[srow];
            bf16x8* dst = (bf16x8*)&Xs[srow][sseg * 16];
            if (t >= 0) {
                dst[0] = loadB8r(x, (size_t)t * DIM + kb * 256 + sseg * 16, xf);
                dst[1] = loadB8r(x, (size_t)t * DIM + kb * 256 + sseg * 16 + 8, xf);
            } else {
                bf16x8 z;
                #pragma unroll
                for (int i = 0; i < 8; i++) z[i] = (bf16_t)0.0f;
                dst[0] = z; dst[1] = z;
            }
        }
        __syncthreads();

        const size_t cb = boff + (size_t)kb * 256;
        #pragma unroll
        for (int k0 = 0; k0 < 128; k0 += 32) {
            bf16x8 a0 = *(const bf16x8*)&Xs[rsel][kq * 8 + k0];
            bf16x8 a1 = *(const bf16x8*)&Xs[rsel][kq * 8 + k0 + 128];
            bf16x8 bg0 = loadB8r(wg, cb + k0,       gf);
            bf16x8 bg1 = loadB8r(wg, cb + k0 + 128, gf);
            bf16x8 bu0 = loadB8r(wu, cb + k0,       uf);
            bf16x8 bu1 = loadB8r(wu, cb + k0 + 128, uf);
            accg0 = __builtin_amdgcn_mfma_f32_16x16x32_bf16(a0, bg0, accg0, 0, 0, 0);
            accg1 = __builtin_amdgcn_mfma_f32_16x16x32_bf16(a1, bg1, accg1, 0, 0, 0);
            accu0 = __builtin_amdgcn_mfma_f32_16x16x32_bf16(a0, bu0, accu0, 0, 0, 0);
            accu1 = __builtin_amdgcn_mfma_f32_16x16x32_bf16(a1, bu1, accu1, 0, 0, 0);
        }
    }

    const int hbase = hoff[e] + mt * 16;
    #pragma unroll
    for (int r = 0; r < 4; r++) {
        float g = accg0[r] + accg1[r];
        float u = accu0[r] + accu1[r];
        H[(size_t)(hbase + kq * 4 + r) * FF + f0 + rsel] = (bf16_t)swiglu(g, u);
    }
}

// ---- down-proj + combine : grid (e, mtile, dtile=8) ----
// Wave owns two 16-col d-tiles; K=512 split into 2 halves -> 4 MFMA chains.
__global__ __launch_bounds__(256, 4) void down_kernel(
    const void* __restrict__ wd,
    const int* __restrict__ flags, const int* __restrict__ cnt,
    const int* __restrict__ hoff, const int* __restrict__ tok_enc,
    const float* __restrict__ selw, const bf16_t* __restrict__ H,
    float* __restrict__ outp)
{
    const int e = blockIdx.x, mt = blockIdx.y, dt = blockIdx.z;
    int C = cnt[e]; if (C > T_TOK) C = T_TOK; if (C < 0) C = 0;
    if (mt * 16 >= C) return;
    const bool df = flags[5] != 0;

    __shared__ __align__(16) bf16_t Hs[16][520];
    __shared__ int toks[16];
    __shared__ float wts[16];
    const int tid = threadIdx.x;
    if (tid < 16) {
        int idx = mt * 16 + tid, t = -1; float w = 0.f;
        if (idx < C) {
            int enc = tok_enc[e * T_TOK + idx];
            int tt = enc & 0xFFFF, kk = (enc >> 16) & 0xFFFF;
            if (tt < T_TOK && kk < 3) { t = tt; w = selw[tt * 3 + kk]; }
        }
        toks[tid] = t; wts[tid] = w;
    }
    __syncthreads();
    {
        int row = tid >> 4, chunk = tid & 15;
        const bf16x8* src = (const bf16x8*)(H + (size_t)(hoff[e] + mt * 16 + row) * FF + chunk * 32);
        bf16x8* dst = (bf16x8*)&Hs[row][chunk * 32];
        #pragma unroll
        for (int i = 0; i < 4; i++) dst[i] = src[i];
    }
    __syncthreads();

    const int wave = tid >> 6, lane = tid & 63;
    const int rsel = lane & 15, kq = lane >> 4;
    const size_t eoffD = (size_t)e * DIM * FF;
    const int d0 = dt * 128 + wave * 32;
    const size_t b0off = eoffD + (size_t)(d0 + rsel) * FF + kq * 8;
    const size_t b1off = eoffD + (size_t)(d0 + 16 + rsel) * FF + kq * 8;

    floatx4 acc00 = {0,0,0,0}, acc01 = {0,0,0,0};
    floatx4 acc10 = {0,0,0,0}, acc11 = {0,0,0,0};
    #pragma unroll
    for (int k0 = 0; k0 < 256; k0 += 32) {
        bf16x8 alo = *(const bf16x8*)&Hs[rsel][kq * 8 + k0];
        bf16x8 ahi = *(const bf16x8*)&Hs[rsel][kq * 8 + k0 + 256];
        bf16x8 b00 = loadB8r(wd, b0off + k0,       df);
        bf16x8 b01 = loadB8r(wd, b0off + k0 + 256, df);
        bf16x8 b10 = loadB8r(wd, b1off + k0,       df);
        bf16x8 b11 = loadB8r(wd, b1off + k0 + 256, df);
        acc00 = __builtin_amdgcn_mfma_f32_16x16x32_bf16(alo, b00, acc00, 0, 0, 0);
        acc01 = __builtin_amdgcn_mfma_f32_16x16x32_bf16(ahi, b01, acc01, 0, 0, 0);
        acc10 = __builtin_amdgcn_mfma_f32_16x16x32_bf16(alo, b10, acc10, 0, 0, 0);
        acc11 = __builtin_amdgcn_mfma_f32_16x16x32_bf16(ahi, b11, acc11, 0, 0, 0);
    }

    #pragma unroll
    for (int r = 0; r < 4; r++) {
        int m = kq * 4 + r, t = toks[m];
        if (t >= 0) {
            atomicAdd(outp + (size_t)t * DIM + d0 + rsel,      (acc00[r] + acc01[r]) * wts[m]);
            atomicAdd(outp + (size_t)t * DIM + d0 + 16 + rsel, (acc10[r] + acc11[r]) * wts[m]);
        }
    }
}

// ---------------- fallback fused FFN (verified r4) ----------------
__global__ __launch_bounds__(256) void ffn_kernel(
    const void* __restrict__ x,
    const void* __restrict__ wg, const void* __restrict__ wu, const void* __restrict__ wd,
    const int* __restrict__ flags, const int* __restrict__ cnt, const int* __restrict__ tok_enc,
    const float* __restrict__ selw, float* __restrict__ outp)
{
    const int e = blockIdx.x, tile = blockIdx.y;
    int C = cnt[e]; if (C > T_TOK) C = T_TOK; if (C < 0) C = 0;
    if (tile * 16 >= C) return;
    const bool xf = flags[0] != 0, gf = flags[3] != 0, uf = flags[4] != 0, df = flags[5] != 0;

    __shared__ __align__(16) bf16_t Xs[16][1032];
    __shared__ __align__(16) bf16_t Hs[16][520];
    __shared__ int toks[16];
    __shared__ float wts[16];
    const int tid = threadIdx.x;
    if (tid < 16) {
        int idx = tile * 16 + tid, t = -1; float w = 0.f;
        if (idx < C) {
            int enc = tok_enc[e * T_TOK + idx];
            int tt = enc & 0xFFFF, kk = (enc >> 16) & 0xFFFF;
            if (tt < T_TOK && kk < 3) { t = tt; w = selw[tt * 3 + kk]; }
        }
        toks[tid] = t; wts[tid] = w;
    }
    __syncthreads();
    {
        int row = tid >> 4, chunk = tid & 15;
        int t = toks[row];
        bf16x8* dst = (bf16x8*)&Xs[row][chunk * 64];
        if (t >= 0) {
            #pragma unroll
            for (int i = 0; i < 8; i++)
                dst[i] = loadB8r(x, (size_t)t * DIM + chunk * 64 + i * 8, xf);
        } else {
            bf16x8 z;
            #pragma unroll
            for (int kz = 0; kz < 8; kz++) z[kz] = (bf16_t)0.0f;
            #pragma unroll
            for (int i = 0; i < 8; i++) dst[i] = z;
        }
    }
    __syncthreads();

    const int wave = tid >> 6, lane = tid & 63;
    const int rsel = lane & 15, kq = lane >> 4;
    const size_t eoffF = (size_t)e * FF * DIM;
    for (int nt = 0; nt < 8; nt++) {
        const int f0 = wave * 128 + nt * 16;
        const size_t boff = eoffF + (size_t)(f0 + rsel) * DIM + kq * 8;
        const bf16_t* ap = &Xs[rsel][kq * 8];
        floatx4 accg = {0.f,0.f,0.f,0.f};
        floatx4 accu = {0.f,0.f,0.f,0.f};
        for (int k0 = 0; k0 < DIM; k0 += 32) {
            bf16x8 a  = *(const bf16x8*)(ap + k0);
            bf16x8 bg = loadB8r(wg, boff + k0, gf);
            bf16x8 bu = loadB8r(wu, boff + k0, uf);
            accg = __builtin_amdgcn_mfma_f32_16x16x32_bf16(a, bg, accg, 0, 0, 0);
            accu = __builtin_amdgcn_mfma_f32_16x16x32_bf16(a, bu, accu, 0, 0, 0);
        }
        #pragma unroll
        for (int r = 0; r < 4; r++)
            Hs[kq * 4 + r][f0 + rsel] = (bf16_t)swiglu(accg[r], accu[r]);
    }
    __syncthreads();
    const size_t eoffD = (size_t)e * DIM * FF;
    for (int nt = 0; nt < 16; nt++) {
        const int d0 = wave * 256 + nt * 16;
        const size_t boff = eoffD + (size_t)(d0 + rsel) * FF + kq * 8;
        const bf16_t* ap = &Hs[rsel][kq * 8];
        floatx4 acc = {0.f,0.f,0.f,0.f};
        for (int k0 = 0; k0 < FF; k0 += 32) {
            bf16x8 a = *(const bf16x8*)(ap + k0);
            bf16x8 b = loadB8r(wd, boff + k0, df);
            acc = __builtin_amdgcn_mfma_f32_16x16x32_bf16(a, b, acc, 0, 0, 0);
        }
        #pragma unroll
        for (int r = 0; r < 4; r++) {
            int m = kq * 4 + r, t = toks[m];
            if (t >= 0) atomicAdd(outp + (size_t)t * DIM + d0 + rsel, acc[r] * wts[m]);
        }
    }
}

extern "C" void kernel_launch(void* const* d_in, const int* in_sizes, int n_in,
                              void* d_out, int out_size, void* d_ws, size_t ws_size,
                              hipStream_t stream)
{
    const void* x     = d_in[0];
    const void* w_out = d_in[1];
    const void* w_in  = d_in[2];
    const void* wg    = d_in[3];
    const void* wu    = d_in[4];
    const void* wd    = d_in[5];
    float* out  = (float*)d_out;
    float* selw = out + (size_t)T_TOK * DIM;

    char* ws = (char*)d_ws;
    int*    flags = (int*)(ws + FLAG_OFF);
    int*    cnt   = (int*)(ws + CNT_OFF);
    int*    hoff  = (int*)(ws + HOFF_OFF);
    int*    tok   = (int*)(ws + TOK_OFF);
    bf16_t* H     = (bf16_t*)(ws + H_OFF);

    hipMemsetAsync(cnt, 0, NEXP * sizeof(int), stream);
    hipMemsetAsync(out, 0, (size_t)T_TOK * DIM * sizeof(float), stream);

    detect_kernel<<<dim3(1), dim3(64), 0, stream>>>(x, w_out, w_in, wg, wu, wd, flags);

    router_kernel<<<dim3(T_TOK), dim3(256), 0, stream>>>(
        x, w_out, w_in, selw, flags, cnt, tok);

    if (ws_size >= (size_t)WS_NEED) {
        hoff_kernel<<<dim3(1), dim3(64), 0, stream>>>(cnt, hoff);
        gateup_kernel<<<dim3(NEXP, 64, 8), dim3(256), 0, stream>>>(
            x, wg, wu, flags, cnt, hoff, tok, H);
        down_kernel<<<dim3(NEXP, 64, 8), dim3(256), 0, stream>>>(
            wd, flags, cnt, hoff, tok, selw, H, out);
    } else {
        ffn_kernel<<<dim3(NEXP, 64), dim3(256), 0, stream>>>(
            x, wg, wu, wd, flags, cnt, tok, selw, out);
    }
}

// Round 7
// 300.592 us; speedup vs baseline: 1.3799x; 1.3799x over previous
//
#include <hip/hip_runtime.h>
#include <hip/hip_bf16.h>

typedef __bf16 bf16_t;
typedef __bf16 bf16x8 __attribute__((ext_vector_type(8)));
typedef float floatx4 __attribute__((ext_vector_type(4)));

#define T_TOK 1024
#define DIM   1024
#define FF    512
#define NEXP  16

// ws layout
#define FLAG_OFF 0                 // int[6]
#define CNT_OFF  64                // int[16]
#define TOK_OFF  256               // int[16*1024], entry = token | (slot<<16)
#define H_OFF    65792             // bf16[3072][512] = 3,145,728 B (row = t*3+slot)
#define WS_NEED  (H_OFF + (size_t)3072*512*2)

__device__ inline float swiglu(float g, float u) {
    float a = fminf(fmaxf(-g, -60.f), 60.f);
    return g * u / (1.0f + __expf(a));
}

// ---------------- per-input dtype detect (verified r4; now 6 blocks) ----------------
__global__ __launch_bounds__(64) void detect_kernel(
    const void* p0, const void* p1, const void* p2,
    const void* p3, const void* p4, const void* p5,
    int* __restrict__ flags)
{
    const void* ps[6] = {p0, p1, p2, p3, p4, p5};
    int j = blockIdx.x;
    int lane = threadIdx.x;
    const unsigned short* h = (const unsigned short*)ps[j];
    unsigned int bad = 0;
    for (int i = lane; i < 4096; i += 64) {
        unsigned int e = ((unsigned int)h[i] >> 7) & 0xFFu;
        if (e >= 0x90u) bad = 1;
    }
    unsigned long long b = __ballot(bad);
    if (lane == 0) flags[j] = (b != 0ull) ? 1 : 0;
}

// ---- runtime-typed loaders ----
__device__ inline void load16fr(const void* base, size_t off, float* o, bool f32) {
    if (f32) {
        const float4* p = (const float4*)((const float*)base + off);
        float4 v0 = p[0], v1 = p[1], v2 = p[2], v3 = p[3];
        o[0]=v0.x; o[1]=v0.y; o[2]=v0.z; o[3]=v0.w;
        o[4]=v1.x; o[5]=v1.y; o[6]=v1.z; o[7]=v1.w;
        o[8]=v2.x; o[9]=v2.y; o[10]=v2.z; o[11]=v2.w;
        o[12]=v3.x; o[13]=v3.y; o[14]=v3.z; o[15]=v3.w;
    } else {
        const bf16x8* p = (const bf16x8*)((const bf16_t*)base + off);
        bf16x8 a = p[0], b = p[1];
        #pragma unroll
        for (int i = 0; i < 8; i++) { o[i] = (float)a[i]; o[8+i] = (float)b[i]; }
    }
}

__device__ inline bf16x8 loadB8r(const void* base, size_t off, bool f32) {
    if (f32) {
        const float4* p = (const float4*)((const float*)base + off);
        float4 v0 = p[0], v1 = p[1];
        bf16x8 r;
        r[0]=(bf16_t)v0.x; r[1]=(bf16_t)v0.y; r[2]=(bf16_t)v0.z; r[3]=(bf16_t)v0.w;
        r[4]=(bf16_t)v1.x; r[5]=(bf16_t)v1.y; r[6]=(bf16_t)v1.z; r[7]=(bf16_t)v1.w;
        return r;
    } else {
        return *(const bf16x8*)((const bf16_t*)base + off);
    }
}

// ---------------- Router: 4 waves per token, 6 gates per wave (verified r5) ----------------
__global__ __launch_bounds__(256) void router_kernel(
    const void* __restrict__ x,
    const void* __restrict__ w_out,   // [8,1024]
    const void* __restrict__ w_in,    // [16,1024]
    float* __restrict__ selw_out,     // [T,3] fp32
    const int* __restrict__ flags,
    int* __restrict__ cnt, int* __restrict__ tok_enc)
{
    const bool xf  = flags[0] != 0;
    const bool gof = flags[1] != 0;
    const bool gif = flags[2] != 0;
    const int t = blockIdx.x;
    const int tid = threadIdx.x;
    const int wave = tid >> 6, lane = tid & 63;

    float xv[16];
    load16fr(x, (size_t)t * DIM + lane * 16, xv, xf);

    __shared__ float logits[24];
    for (int j = wave; j < 24; j += 4) {
        const void* grow = (j < 8) ? w_out : w_in;
        size_t roff = (j < 8) ? (size_t)j * DIM : (size_t)(j - 8) * DIM;
        float gv[16];
        load16fr(grow, roff + lane * 16, gv, (j < 8) ? gof : gif);
        float s = 0.f;
        #pragma unroll
        for (int i = 0; i < 16; i++) s += xv[i] * gv[i];
        #pragma unroll
        for (int m = 32; m >= 1; m >>= 1) s += __shfl_xor(s, m, 64);
        if (lane == 0) logits[j] = s;
    }
    __syncthreads();

    if (tid == 0) {
        float mx = logits[0];
        for (int o = 1; o < 8; o++) mx = fmaxf(mx, logits[o]);
        float p[8];
        for (int o = 0; o < 8; o++) p[o] = __expf(logits[o] - mx);
        int i0 = 0;
        for (int o = 1; o < 8; o++) if (logits[o] > logits[i0]) i0 = o;
        int i1 = (i0 == 0) ? 1 : 0;
        for (int o = 0; o < 8; o++) if (o != i0 && logits[o] > logits[i1]) i1 = o;
        float rsum = p[i0] + p[i1];
        float rw0 = p[i0] / rsum, rw1 = p[i1] / rsum;

        float a0 = logits[8 + i0 * 2], a1 = logits[8 + i0 * 2 + 1];
        int j00 = (a1 > a0) ? 1 : 0;
        float b0 = logits[8 + i1 * 2], b1 = logits[8 + i1 * 2 + 1];
        int j10 = (b1 > b0) ? 1 : 0;

        int   ids[3] = { i0 * 2 + j00, i0 * 2 + (1 - j00), i1 * 2 + j10 };
        float w[3]   = { rw0, rw0, rw1 };

        #pragma unroll
        for (int k = 0; k < 3; k++) {
            selw_out[t * 3 + k] = w[k];
            int e = ids[k];
            int pos = atomicAdd(&cnt[e], 1);
            if (pos >= 0 && pos < T_TOK)
                tok_enc[e * T_TOK + pos] = t | (k << 16);
        }
    }
}

// ---- gate+up+SwiGLU -> H : grid (e, mtile64, ftile=8) ----
// M=64 token tile; wave owns 16 F-cols; B-fragments reused across 4 m-subtiles
// (8 independent MFMA chains). X staged in 4 K-chunks of 256. H row = t*3+slot.
__global__ __launch_bounds__(256, 2) void gateup_kernel(
    const void* __restrict__ x,
    const void* __restrict__ wg, const void* __restrict__ wu,
    const int* __restrict__ flags, const int* __restrict__ cnt,
    const int* __restrict__ tok_enc,
    bf16_t* __restrict__ H)
{
    const int e = blockIdx.x, mt = blockIdx.y, ft = blockIdx.z;
    int C = cnt[e]; if (C > T_TOK) C = T_TOK; if (C < 0) C = 0;
    if (mt * 64 >= C) return;
    const bool xf = flags[0] != 0, gf = flags[3] != 0, uf = flags[4] != 0;

    __shared__ __align__(16) bf16_t Xs[64][264];   // one 256-wide K chunk (33.8 KB)
    __shared__ int toks[64];
    __shared__ int hrow[64];

    const int tid = threadIdx.x;
    if (tid < 64) {
        int idx = mt * 64 + tid, t = -1, hr = -1;
        if (idx < C) {
            int enc = tok_enc[e * T_TOK + idx];
            int tt = enc & 0xFFFF, kk = (enc >> 16) & 0xFFFF;
            if (tt < T_TOK && kk < 3) { t = tt; hr = tt * 3 + kk; }
        }
        toks[tid] = t; hrow[tid] = hr;
    }

    const int wave = tid >> 6, lane = tid & 63;
    const int rsel = lane & 15, kq = lane >> 4;
    const int srow = tid >> 2, sseg = tid & 3;      // staging: 64 rows x 4 segs(64 elems)
    const size_t eoffF = (size_t)e * FF * DIM;
    const int f0 = ft * 64 + wave * 16;
    const size_t boff = eoffF + (size_t)(f0 + rsel) * DIM + kq * 8;

    floatx4 ag[4], au[4];
    #pragma unroll
    for (int ms = 0; ms < 4; ms++) { ag[ms] = (floatx4){0,0,0,0}; au[ms] = (floatx4){0,0,0,0}; }

    for (int kb = 0; kb < 4; kb++) {
        __syncthreads();
        {
            int t = toks[srow];
            bf16x8* dst = (bf16x8*)&Xs[srow][sseg * 64];
            if (t >= 0) {
                #pragma unroll
                for (int i = 0; i < 8; i++)
                    dst[i] = loadB8r(x, (size_t)t * DIM + kb * 256 + sseg * 64 + i * 8, xf);
            } else {
                bf16x8 z;
                #pragma unroll
                for (int i = 0; i < 8; i++) z[i] = (bf16_t)0.0f;
                #pragma unroll
                for (int i = 0; i < 8; i++) dst[i] = z;
            }
        }
        __syncthreads();

        const size_t cb = boff + (size_t)kb * 256;
        #pragma unroll
        for (int k0 = 0; k0 < 256; k0 += 32) {
            bf16x8 bg = loadB8r(wg, cb + k0, gf);
            bf16x8 bu = loadB8r(wu, cb + k0, uf);
            #pragma unroll
            for (int ms = 0; ms < 4; ms++) {
                bf16x8 a = *(const bf16x8*)&Xs[ms * 16 + rsel][kq * 8 + k0];
                ag[ms] = __builtin_amdgcn_mfma_f32_16x16x32_bf16(a, bg, ag[ms], 0, 0, 0);
                au[ms] = __builtin_amdgcn_mfma_f32_16x16x32_bf16(a, bu, au[ms], 0, 0, 0);
            }
        }
    }

    #pragma unroll
    for (int ms = 0; ms < 4; ms++) {
        #pragma unroll
        for (int r = 0; r < 4; r++) {
            int m = ms * 16 + kq * 4 + r;
            int hr = hrow[m];
            if (hr >= 0)
                H[(size_t)hr * FF + f0 + rsel] = (bf16_t)swiglu(ag[ms][r], au[ms][r]);
        }
    }
}

// ---- down-proj + combine : grid (e, mtile64, dtile=16) ----
// M=64; full H tile (64x512) staged once; B reused across 4 m-subtiles.
__global__ __launch_bounds__(256, 2) void down_kernel(
    const void* __restrict__ wd,
    const int* __restrict__ flags, const int* __restrict__ cnt,
    const int* __restrict__ tok_enc,
    const float* __restrict__ selw, const bf16_t* __restrict__ H,
    float* __restrict__ outp)
{
    const int e = blockIdx.x, mt = blockIdx.y, dt = blockIdx.z;
    int C = cnt[e]; if (C > T_TOK) C = T_TOK; if (C < 0) C = 0;
    if (mt * 64 >= C) return;
    const bool df = flags[5] != 0;

    __shared__ __align__(16) bf16_t Hs[64][520];   // 66.6 KB
    __shared__ int toks[64];
    __shared__ float wts[64];
    __shared__ int hrow[64];

    const int tid = threadIdx.x;
    if (tid < 64) {
        int idx = mt * 64 + tid, t = -1, hr = -1; float w = 0.f;
        if (idx < C) {
            int enc = tok_enc[e * T_TOK + idx];
            int tt = enc & 0xFFFF, kk = (enc >> 16) & 0xFFFF;
            if (tt < T_TOK && kk < 3) { t = tt; hr = tt * 3 + kk; w = selw[tt * 3 + kk]; }
        }
        toks[tid] = t; wts[tid] = w; hrow[tid] = hr;
    }
    __syncthreads();
    {
        int row = tid >> 2, seg = tid & 3;         // 4 segs x 128 elems
        int hr = hrow[row];
        bf16x8* dst = (bf16x8*)&Hs[row][seg * 128];
        if (hr >= 0) {
            const bf16x8* src = (const bf16x8*)(H + (size_t)hr * FF + seg * 128);
            #pragma unroll
            for (int i = 0; i < 16; i++) dst[i] = src[i];
        } else {
            bf16x8 z;
            #pragma unroll
            for (int i = 0; i < 8; i++) z[i] = (bf16_t)0.0f;
            #pragma unroll
            for (int i = 0; i < 16; i++) dst[i] = z;
        }
    }
    __syncthreads();

    const int wave = tid >> 6, lane = tid & 63;
    const int rsel = lane & 15, kq = lane >> 4;
    const size_t eoffD = (size_t)e * DIM * FF;
    const int d0 = dt * 64 + wave * 16;
    const size_t boff = eoffD + (size_t)(d0 + rsel) * FF + kq * 8;

    floatx4 acc[4];
    #pragma unroll
    for (int ms = 0; ms < 4; ms++) acc[ms] = (floatx4){0,0,0,0};

    #pragma unroll
    for (int k0 = 0; k0 < FF; k0 += 32) {
        bf16x8 b = loadB8r(wd, boff + k0, df);
        #pragma unroll
        for (int ms = 0; ms < 4; ms++) {
            bf16x8 a = *(const bf16x8*)&Hs[ms * 16 + rsel][kq * 8 + k0];
            acc[ms] = __builtin_amdgcn_mfma_f32_16x16x32_bf16(a, b, acc[ms], 0, 0, 0);
        }
    }

    #pragma unroll
    for (int ms = 0; ms < 4; ms++) {
        #pragma unroll
        for (int r = 0; r < 4; r++) {
            int m = ms * 16 + kq * 4 + r, t = toks[m];
            if (t >= 0)
                atomicAdd(outp + (size_t)t * DIM + d0 + rsel, acc[ms][r] * wts[m]);
        }
    }
}

// ---------------- fallback fused FFN (verified r4) ----------------
__global__ __launch_bounds__(256) void ffn_kernel(
    const void* __restrict__ x,
    const void* __restrict__ wg, const void* __restrict__ wu, const void* __restrict__ wd,
    const int* __restrict__ flags, const int* __restrict__ cnt, const int* __restrict__ tok_enc,
    const float* __restrict__ selw, float* __restrict__ outp)
{
    const int e = blockIdx.x, tile = blockIdx.y;
    int C = cnt[e]; if (C > T_TOK) C = T_TOK; if (C < 0) C = 0;
    if (tile * 16 >= C) return;
    const bool xf = flags[0] != 0, gf = flags[3] != 0, uf = flags[4] != 0, df = flags[5] != 0;

    __shared__ __align__(16) bf16_t Xs[16][1032];
    __shared__ __align__(16) bf16_t Hs[16][520];
    __shared__ int toks[16];
    __shared__ float wts[16];
    const int tid = threadIdx.x;
    if (tid < 16) {
        int idx = tile * 16 + tid, t = -1; float w = 0.f;
        if (idx < C) {
            int enc = tok_enc[e * T_TOK + idx];
            int tt = enc & 0xFFFF, kk = (enc >> 16) & 0xFFFF;
            if (tt < T_TOK && kk < 3) { t = tt; w = selw[tt * 3 + kk]; }
        }
        toks[tid] = t; wts[tid] = w;
    }
    __syncthreads();
    {
        int row = tid >> 4, chunk = tid & 15;
        int t = toks[row];
        bf16x8* dst = (bf16x8*)&Xs[row][chunk * 64];
        if (t >= 0) {
            #pragma unroll
            for (int i = 0; i < 8; i++)
                dst[i] = loadB8r(x, (size_t)t * DIM + chunk * 64 + i * 8, xf);
        } else {
            bf16x8 z;
            #pragma unroll
            for (int kz = 0; kz < 8; kz++) z[kz] = (bf16_t)0.0f;
            #pragma unroll
            for (int i = 0; i < 8; i++) dst[i] = z;
        }
    }
    __syncthreads();

    const int wave = tid >> 6, lane = tid & 63;
    const int rsel = lane & 15, kq = lane >> 4;
    const size_t eoffF = (size_t)e * FF * DIM;
    for (int nt = 0; nt < 8; nt++) {
        const int f0 = wave * 128 + nt * 16;
        const size_t boff = eoffF + (size_t)(f0 + rsel) * DIM + kq * 8;
        const bf16_t* ap = &Xs[rsel][kq * 8];
        floatx4 accg = {0.f,0.f,0.f,0.f};
        floatx4 accu = {0.f,0.f,0.f,0.f};
        for (int k0 = 0; k0 < DIM; k0 += 32) {
            bf16x8 a  = *(const bf16x8*)(ap + k0);
            bf16x8 bg = loadB8r(wg, boff + k0, gf);
            bf16x8 bu = loadB8r(wu, boff + k0, uf);
            accg = __builtin_amdgcn_mfma_f32_16x16x32_bf16(a, bg, accg, 0, 0, 0);
            accu = __builtin_amdgcn_mfma_f32_16x16x32_bf16(a, bu, accu, 0, 0, 0);
        }
        #pragma unroll
        for (int r = 0; r < 4; r++)
            Hs[kq * 4 + r][f0 + rsel] = (bf16_t)swiglu(accg[r], accu[r]);
    }
    __syncthreads();
    const size_t eoffD = (size_t)e * DIM * FF;
    for (int nt = 0; nt < 16; nt++) {
        const int d0 = wave * 256 + nt * 16;
        const size_t boff = eoffD + (size_t)(d0 + rsel) * FF + kq * 8;
        const bf16_t* ap = &Hs[rsel][kq * 8];
        floatx4 acc = {0.f,0.f,0.f,0.f};
        for (int k0 = 0; k0 < FF; k0 += 32) {
            bf16x8 a = *(const bf16x8*)(ap + k0);
            bf16x8 b = loadB8r(wd, boff + k0, df);
            acc = __builtin_amdgcn_mfma_f32_16x16x32_bf16(a, b, acc, 0, 0, 0);
        }
        #pragma unroll
        for (int r = 0; r < 4; r++) {
            int m = kq * 4 + r, t = toks[m];
            if (t >= 0) atomicAdd(outp + (size_t)t * DIM + d0 + rsel, acc[r] * wts[m]);
        }
    }
}

extern "C" void kernel_launch(void* const* d_in, const int* in_sizes, int n_in,
                              void* d_out, int out_size, void* d_ws, size_t ws_size,
                              hipStream_t stream)
{
    const void* x     = d_in[0];
    const void* w_out = d_in[1];
    const void* w_in  = d_in[2];
    const void* wg    = d_in[3];
    const void* wu    = d_in[4];
    const void* wd    = d_in[5];
    float* out  = (float*)d_out;
    float* selw = out + (size_t)T_TOK * DIM;

    char* ws = (char*)d_ws;
    int*    flags = (int*)(ws + FLAG_OFF);
    int*    cnt   = (int*)(ws + CNT_OFF);
    int*    tok   = (int*)(ws + TOK_OFF);
    bf16_t* H     = (bf16_t*)(ws + H_OFF);

    hipMemsetAsync(cnt, 0, NEXP * sizeof(int), stream);
    hipMemsetAsync(out, 0, (size_t)T_TOK * DIM * sizeof(float), stream);

    detect_kernel<<<dim3(6), dim3(64), 0, stream>>>(x, w_out, w_in, wg, wu, wd, flags);

    router_kernel<<<dim3(T_TOK), dim3(256), 0, stream>>>(
        x, w_out, w_in, selw, flags, cnt, tok);

    if (ws_size >= (size_t)WS_NEED) {
        gateup_kernel<<<dim3(NEXP, 16, 8), dim3(256), 0, stream>>>(
            x, wg, wu, flags, cnt, tok, H);
        down_kernel<<<dim3(NEXP, 16, 16), dim3(256), 0, stream>>>(
            wd, flags, cnt, tok, selw, H, out);
    } else {
        ffn_kernel<<<dim3(NEXP, 64), dim3(256), 0, stream>>>(
            x, wg, wu, wd, flags, cnt, tok, selw, out);
    }
}

// Round 8
// 298.154 us; speedup vs baseline: 1.3912x; 1.0082x over previous
//
#include <hip/hip_runtime.h>
#include <hip/hip_bf16.h>

typedef __bf16 bf16_t;
typedef __bf16 bf16x8 __attribute__((ext_vector_type(8)));
typedef float floatx4 __attribute__((ext_vector_type(4)));

#define T_TOK 1024
#define DIM   1024
#define FF    512
#define NEXP  16

// ws layout
#define FLAG_OFF 0                 // int[6]
#define CNT_OFF  64                // int[16]
#define TOK_OFF  256               // int[16*1024], entry = token | (slot<<16)
#define H_OFF    65792             // bf16[3072][512] (row = t*3+slot)
#define WS_NEED  (H_OFF + (size_t)3072*512*2)

__device__ inline float swiglu(float g, float u) {
    float a = fminf(fmaxf(-g, -60.f), 60.f);
    return g * u / (1.0f + __expf(a));
}

// ---------------- per-input dtype detect (verified r4) ----------------
__global__ __launch_bounds__(64) void detect_kernel(
    const void* p0, const void* p1, const void* p2,
    const void* p3, const void* p4, const void* p5,
    int* __restrict__ flags)
{
    const void* ps[6] = {p0, p1, p2, p3, p4, p5};
    int j = blockIdx.x;
    int lane = threadIdx.x;
    const unsigned short* h = (const unsigned short*)ps[j];
    unsigned int bad = 0;
    for (int i = lane; i < 4096; i += 64) {
        unsigned int e = ((unsigned int)h[i] >> 7) & 0xFFu;
        if (e >= 0x90u) bad = 1;
    }
    unsigned long long b = __ballot(bad);
    if (lane == 0) flags[j] = (b != 0ull) ? 1 : 0;
}

// ---- runtime-typed loaders ----
__device__ inline bf16x8 loadB8r(const void* base, size_t off, bool f32) {
    if (f32) {
        const float4* p = (const float4*)((const float*)base + off);
        float4 v0 = p[0], v1 = p[1];
        bf16x8 r;
        r[0]=(bf16_t)v0.x; r[1]=(bf16_t)v0.y; r[2]=(bf16_t)v0.z; r[3]=(bf16_t)v0.w;
        r[4]=(bf16_t)v1.x; r[5]=(bf16_t)v1.y; r[6]=(bf16_t)v1.z; r[7]=(bf16_t)v1.w;
        return r;
    } else {
        return *(const bf16x8*)((const bf16_t*)base + off);
    }
}

__device__ inline float bfbits(unsigned short u) {
    return __uint_as_float(((unsigned int)u) << 16);
}

// ---------------- Router: 256 blocks x 4 tokens; gates staged in LDS ----------------
__global__ __launch_bounds__(256) void router_kernel(
    const void* __restrict__ x,
    const void* __restrict__ w_out,   // [8,1024]
    const void* __restrict__ w_in,    // [16,1024]
    float* __restrict__ selw_out,     // [T,3] fp32
    const int* __restrict__ flags,
    int* __restrict__ cnt, int* __restrict__ tok_enc)
{
    const bool xf  = flags[0] != 0;
    const bool gof = flags[1] != 0;
    const bool gif = flags[2] != 0;
    const int tid = threadIdx.x;

    __shared__ __align__(16) float Gs[24 * 1024];   // 96 KB
    __shared__ float Ls[4][24];

    // stage w_out (8 rows) + w_in (16 rows), vectorized
    if (gof) {
        const float4* s = (const float4*)w_out; float4* d = (float4*)Gs;
        for (int i = tid; i < 2048; i += 256) d[i] = s[i];
    } else {
        const ushort4* s = (const ushort4*)w_out; float4* d = (float4*)Gs;
        for (int i = tid; i < 2048; i += 256) {
            ushort4 v = s[i];
            d[i] = make_float4(bfbits(v.x), bfbits(v.y), bfbits(v.z), bfbits(v.w));
        }
    }
    if (gif) {
        const float4* s = (const float4*)w_in; float4* d = (float4*)(Gs + 8 * 1024);
        for (int i = tid; i < 4096; i += 256) d[i] = s[i];
    } else {
        const ushort4* s = (const ushort4*)w_in; float4* d = (float4*)(Gs + 8 * 1024);
        for (int i = tid; i < 4096; i += 256) {
            ushort4 v = s[i];
            d[i] = make_float4(bfbits(v.x), bfbits(v.y), bfbits(v.z), bfbits(v.w));
        }
    }
    __syncthreads();

    const int wave = tid >> 6, lane = tid & 63;
    const int t = blockIdx.x * 4 + wave;

    // x fragment: elements lane + 64*i (coalesced; LDS reads 2-way alias = free)
    float xv[16];
    if (xf) {
        const float* xp = (const float*)x + (size_t)t * DIM;
        #pragma unroll
        for (int i = 0; i < 16; i++) xv[i] = xp[lane + 64 * i];
    } else {
        const bf16_t* xp = (const bf16_t*)x + (size_t)t * DIM;
        #pragma unroll
        for (int i = 0; i < 16; i++) xv[i] = (float)xp[lane + 64 * i];
    }

    for (int j = 0; j < 24; j++) {
        const float* g = &Gs[j * 1024];
        float s = 0.f;
        #pragma unroll
        for (int i = 0; i < 16; i++) s += xv[i] * g[lane + 64 * i];
        #pragma unroll
        for (int m = 32; m >= 1; m >>= 1) s += __shfl_xor(s, m, 64);
        if (lane == 0) Ls[wave][j] = s;
    }

    if (lane == 0) {
        const float* logits = Ls[wave];
        float mx = logits[0];
        for (int o = 1; o < 8; o++) mx = fmaxf(mx, logits[o]);
        float p[8];
        for (int o = 0; o < 8; o++) p[o] = __expf(logits[o] - mx);
        int i0 = 0;
        for (int o = 1; o < 8; o++) if (logits[o] > logits[i0]) i0 = o;
        int i1 = (i0 == 0) ? 1 : 0;
        for (int o = 0; o < 8; o++) if (o != i0 && logits[o] > logits[i1]) i1 = o;
        float rsum = p[i0] + p[i1];
        float rw0 = p[i0] / rsum, rw1 = p[i1] / rsum;

        float a0 = logits[8 + i0 * 2], a1 = logits[8 + i0 * 2 + 1];
        int j00 = (a1 > a0) ? 1 : 0;
        float b0 = logits[8 + i1 * 2], b1 = logits[8 + i1 * 2 + 1];
        int j10 = (b1 > b0) ? 1 : 0;

        int   ids[3] = { i0 * 2 + j00, i0 * 2 + (1 - j00), i1 * 2 + j10 };
        float w[3]   = { rw0, rw0, rw1 };

        #pragma unroll
        for (int k = 0; k < 3; k++) {
            selw_out[t * 3 + k] = w[k];
            int e = ids[k];
            int pos = atomicAdd(&cnt[e], 1);
            if (pos >= 0 && pos < T_TOK)
                tok_enc[e * T_TOK + pos] = t | (k << 16);
        }
    }
}

// ---- gate+up+SwiGLU -> H : grid (e, mtile64, ftile=8) ----
// Per K-chunk: burst-prefetch ALL 16 B-fragments into registers (32 dwordx4
// in flight), stage X, then MFMA from registers. H row = t*3+slot.
__global__ __launch_bounds__(256, 2) void gateup_kernel(
    const void* __restrict__ x,
    const void* __restrict__ wg, const void* __restrict__ wu,
    const int* __restrict__ flags, const int* __restrict__ cnt,
    const int* __restrict__ tok_enc,
    bf16_t* __restrict__ H)
{
    const int e = blockIdx.x, mt = blockIdx.y, ft = blockIdx.z;
    int C = cnt[e]; if (C > T_TOK) C = T_TOK; if (C < 0) C = 0;
    if (mt * 64 >= C) return;
    const bool xf = flags[0] != 0, gf = flags[3] != 0, uf = flags[4] != 0;

    __shared__ __align__(16) bf16_t Xs[64][264];
    __shared__ int toks[64];
    __shared__ int hrow[64];

    const int tid = threadIdx.x;
    if (tid < 64) {
        int idx = mt * 64 + tid, t = -1, hr = -1;
        if (idx < C) {
            int enc = tok_enc[e * T_TOK + idx];
            int tt = enc & 0xFFFF, kk = (enc >> 16) & 0xFFFF;
            if (tt < T_TOK && kk < 3) { t = tt; hr = tt * 3 + kk; }
        }
        toks[tid] = t; hrow[tid] = hr;
    }

    const int wave = tid >> 6, lane = tid & 63;
    const int rsel = lane & 15, kq = lane >> 4;
    const int srow = tid >> 2, sseg = tid & 3;
    const size_t eoffF = (size_t)e * FF * DIM;
    const int f0 = ft * 64 + wave * 16;
    const size_t boff = eoffF + (size_t)(f0 + rsel) * DIM + kq * 8;

    floatx4 ag[4], au[4];
    #pragma unroll
    for (int ms = 0; ms < 4; ms++) { ag[ms] = (floatx4){0,0,0,0}; au[ms] = (floatx4){0,0,0,0}; }

    for (int kb = 0; kb < 4; kb++) {
        const size_t cb = boff + (size_t)kb * 256;
        // burst-prefetch the whole K-chunk's B fragments
        bf16x8 BG[8], BU[8];
        #pragma unroll
        for (int i = 0; i < 8; i++) BG[i] = loadB8r(wg, cb + i * 32, gf);
        #pragma unroll
        for (int i = 0; i < 8; i++) BU[i] = loadB8r(wu, cb + i * 32, uf);

        __syncthreads();
        {
            int t = toks[srow];
            bf16x8* dst = (bf16x8*)&Xs[srow][sseg * 64];
            if (t >= 0) {
                #pragma unroll
                for (int i = 0; i < 8; i++)
                    dst[i] = loadB8r(x, (size_t)t * DIM + kb * 256 + sseg * 64 + i * 8, xf);
            } else {
                bf16x8 z;
                #pragma unroll
                for (int i = 0; i < 8; i++) z[i] = (bf16_t)0.0f;
                #pragma unroll
                for (int i = 0; i < 8; i++) dst[i] = z;
            }
        }
        __syncthreads();

        #pragma unroll
        for (int i = 0; i < 8; i++) {
            #pragma unroll
            for (int ms = 0; ms < 4; ms++) {
                bf16x8 a = *(const bf16x8*)&Xs[ms * 16 + rsel][kq * 8 + i * 32];
                ag[ms] = __builtin_amdgcn_mfma_f32_16x16x32_bf16(a, BG[i], ag[ms], 0, 0, 0);
                au[ms] = __builtin_amdgcn_mfma_f32_16x16x32_bf16(a, BU[i], au[ms], 0, 0, 0);
            }
        }
    }

    #pragma unroll
    for (int ms = 0; ms < 4; ms++) {
        #pragma unroll
        for (int r = 0; r < 4; r++) {
            int m = ms * 16 + kq * 4 + r;
            int hr = hrow[m];
            if (hr >= 0)
                H[(size_t)hr * FF + f0 + rsel] = (bf16_t)swiglu(ag[ms][r], au[ms][r]);
        }
    }
}

// ---- down-proj + combine : grid (e, mtile64, dtile=16) ----
__global__ __launch_bounds__(256, 2) void down_kernel(
    const void* __restrict__ wd,
    const int* __restrict__ flags, const int* __restrict__ cnt,
    const int* __restrict__ tok_enc,
    const float* __restrict__ selw, const bf16_t* __restrict__ H,
    float* __restrict__ outp)
{
    const int e = blockIdx.x, mt = blockIdx.y, dt = blockIdx.z;
    int C = cnt[e]; if (C > T_TOK) C = T_TOK; if (C < 0) C = 0;
    if (mt * 64 >= C) return;
    const bool df = flags[5] != 0;

    __shared__ __align__(16) bf16_t Hs[64][520];
    __shared__ int toks[64];
    __shared__ float wts[64];
    __shared__ int hrow[64];

    const int tid = threadIdx.x;
    if (tid < 64) {
        int idx = mt * 64 + tid, t = -1, hr = -1; float w = 0.f;
        if (idx < C) {
            int enc = tok_enc[e * T_TOK + idx];
            int tt = enc & 0xFFFF, kk = (enc >> 16) & 0xFFFF;
            if (tt < T_TOK && kk < 3) { t = tt; hr = tt * 3 + kk; w = selw[tt * 3 + kk]; }
        }
        toks[tid] = t; wts[tid] = w; hrow[tid] = hr;
    }

    const int wave = tid >> 6, lane = tid & 63;
    const int rsel = lane & 15, kq = lane >> 4;
    const size_t eoffD = (size_t)e * DIM * FF;
    const int d0 = dt * 64 + wave * 16;
    const size_t boff = eoffD + (size_t)(d0 + rsel) * FF + kq * 8;

    // burst-prefetch all 16 B fragments for K=512
    bf16x8 BD[16];
    #pragma unroll
    for (int i = 0; i < 16; i++) BD[i] = loadB8r(wd, boff + i * 32, df);

    __syncthreads();
    {
        int row = tid >> 2, seg = tid & 3;
        int hr = hrow[row];
        bf16x8* dst = (bf16x8*)&Hs[row][seg * 128];
        if (hr >= 0) {
            const bf16x8* src = (const bf16x8*)(H + (size_t)hr * FF + seg * 128);
            #pragma unroll
            for (int i = 0; i < 16; i++) dst[i] = src[i];
        } else {
            bf16x8 z;
            #pragma unroll
            for (int i = 0; i < 8; i++) z[i] = (bf16_t)0.0f;
            #pragma unroll
            for (int i = 0; i < 16; i++) dst[i] = z;
        }
    }
    __syncthreads();

    floatx4 acc[4];
    #pragma unroll
    for (int ms = 0; ms < 4; ms++) acc[ms] = (floatx4){0,0,0,0};

    #pragma unroll
    for (int i = 0; i < 16; i++) {
        #pragma unroll
        for (int ms = 0; ms < 4; ms++) {
            bf16x8 a = *(const bf16x8*)&Hs[ms * 16 + rsel][kq * 8 + i * 32];
            acc[ms] = __builtin_amdgcn_mfma_f32_16x16x32_bf16(a, BD[i], acc[ms], 0, 0, 0);
        }
    }

    #pragma unroll
    for (int ms = 0; ms < 4; ms++) {
        #pragma unroll
        for (int r = 0; r < 4; r++) {
            int m = ms * 16 + kq * 4 + r, t = toks[m];
            if (t >= 0)
                atomicAdd(outp + (size_t)t * DIM + d0 + rsel, acc[ms][r] * wts[m]);
        }
    }
}

// ---------------- fallback fused FFN (verified r4) ----------------
__global__ __launch_bounds__(256) void ffn_kernel(
    const void* __restrict__ x,
    const void* __restrict__ wg, const void* __restrict__ wu, const void* __restrict__ wd,
    const int* __restrict__ flags, const int* __restrict__ cnt, const int* __restrict__ tok_enc,
    const float* __restrict__ selw, float* __restrict__ outp)
{
    const int e = blockIdx.x, tile = blockIdx.y;
    int C = cnt[e]; if (C > T_TOK) C = T_TOK; if (C < 0) C = 0;
    if (tile * 16 >= C) return;
    const bool xf = flags[0] != 0, gf = flags[3] != 0, uf = flags[4] != 0, df = flags[5] != 0;

    __shared__ __align__(16) bf16_t Xs[16][1032];
    __shared__ __align__(16) bf16_t Hs[16][520];
    __shared__ int toks[16];
    __shared__ float wts[16];
    const int tid = threadIdx.x;
    if (tid < 16) {
        int idx = tile * 16 + tid, t = -1; float w = 0.f;
        if (idx < C) {
            int enc = tok_enc[e * T_TOK + idx];
            int tt = enc & 0xFFFF, kk = (enc >> 16) & 0xFFFF;
            if (tt < T_TOK && kk < 3) { t = tt; w = selw[tt * 3 + kk]; }
        }
        toks[tid] = t; wts[tid] = w;
    }
    __syncthreads();
    {
        int row = tid >> 4, chunk = tid & 15;
        int t = toks[row];
        bf16x8* dst = (bf16x8*)&Xs[row][chunk * 64];
        if (t >= 0) {
            #pragma unroll
            for (int i = 0; i < 8; i++)
                dst[i] = loadB8r(x, (size_t)t * DIM + chunk * 64 + i * 8, xf);
        } else {
            bf16x8 z;
            #pragma unroll
            for (int kz = 0; kz < 8; kz++) z[kz] = (bf16_t)0.0f;
            #pragma unroll
            for (int i = 0; i < 8; i++) dst[i] = z;
        }
    }
    __syncthreads();

    const int wave = tid >> 6, lane = tid & 63;
    const int rsel = lane & 15, kq = lane >> 4;
    const size_t eoffF = (size_t)e * FF * DIM;
    for (int nt = 0; nt < 8; nt++) {
        const int f0 = wave * 128 + nt * 16;
        const size_t boff = eoffF + (size_t)(f0 + rsel) * DIM + kq * 8;
        const bf16_t* ap = &Xs[rsel][kq * 8];
        floatx4 accg = {0.f,0.f,0.f,0.f};
        floatx4 accu = {0.f,0.f,0.f,0.f};
        for (int k0 = 0; k0 < DIM; k0 += 32) {
            bf16x8 a  = *(const bf16x8*)(ap + k0);
            bf16x8 bg = loadB8r(wg, boff + k0, gf);
            bf16x8 bu = loadB8r(wu, boff + k0, uf);
            accg = __builtin_amdgcn_mfma_f32_16x16x32_bf16(a, bg, accg, 0, 0, 0);
            accu = __builtin_amdgcn_mfma_f32_16x16x32_bf16(a, bu, accu, 0, 0, 0);
        }
        #pragma unroll
        for (int r = 0; r < 4; r++)
            Hs[kq * 4 + r][f0 + rsel] = (bf16_t)swiglu(accg[r], accu[r]);
    }
    __syncthreads();
    const size_t eoffD = (size_t)e * DIM * FF;
    for (int nt = 0; nt < 16; nt++) {
        const int d0 = wave * 256 + nt * 16;
        const size_t boff = eoffD + (size_t)(d0 + rsel) * FF + kq * 8;
        const bf16_t* ap = &Hs[rsel][kq * 8];
        floatx4 acc = {0.f,0.f,0.f,0.f};
        for (int k0 = 0; k0 < FF; k0 += 32) {
            bf16x8 a = *(const bf16x8*)(ap + k0);
            bf16x8 b = loadB8r(wd, boff + k0, df);
            acc = __builtin_amdgcn_mfma_f32_16x16x32_bf16(a, b, acc, 0, 0, 0);
        }
        #pragma unroll
        for (int r = 0; r < 4; r++) {
            int m = kq * 4 + r, t = toks[m];
            if (t >= 0) atomicAdd(outp + (size_t)t * DIM + d0 + rsel, acc[r] * wts[m]);
        }
    }
}

extern "C" void kernel_launch(void* const* d_in, const int* in_sizes, int n_in,
                              void* d_out, int out_size, void* d_ws, size_t ws_size,
                              hipStream_t stream)
{
    const void* x     = d_in[0];
    const void* w_out = d_in[1];
    const void* w_in  = d_in[2];
    const void* wg    = d_in[3];
    const void* wu    = d_in[4];
    const void* wd    = d_in[5];
    float* out  = (float*)d_out;
    float* selw = out + (size_t)T_TOK * DIM;

    char* ws = (char*)d_ws;
    int*    flags = (int*)(ws + FLAG_OFF);
    int*    cnt   = (int*)(ws + CNT_OFF);
    int*    tok   = (int*)(ws + TOK_OFF);
    bf16_t* H     = (bf16_t*)(ws + H_OFF);

    hipMemsetAsync(cnt, 0, NEXP * sizeof(int), stream);
    hipMemsetAsync(out, 0, (size_t)T_TOK * DIM * sizeof(float), stream);

    detect_kernel<<<dim3(6), dim3(64), 0, stream>>>(x, w_out, w_in, wg, wu, wd, flags);

    router_kernel<<<dim3(T_TOK / 4), dim3(256), 0, stream>>>(
        x, w_out, w_in, selw, flags, cnt, tok);

    if (ws_size >= (size_t)WS_NEED) {
        gateup_kernel<<<dim3(NEXP, 16, 8), dim3(256), 0, stream>>>(
            x, wg, wu, flags, cnt, tok, H);
        down_kernel<<<dim3(NEXP, 16, 16), dim3(256), 0, stream>>>(
            wd, flags, cnt, tok, selw, H, out);
    } else {
        ffn_kernel<<<dim3(NEXP, 64), dim3(256), 0, stream>>>(
            x, wg, wu, wd, flags, cnt, tok, selw, out);
    }
}